// Round 2
// baseline (2051.966 us; speedup 1.0000x reference)
//
#include <hip/hip_runtime.h>
#include <hip/hip_bf16.h>
#include <stdint.h>

#define D 64
typedef __hip_bfloat16 bf16;
typedef unsigned short u16;

__device__ __forceinline__ float bf2f(u16 u) { return __uint_as_float(((uint32_t)u) << 16); }

template <bool F32>
__device__ __forceinline__ float ld(const void* p, int i) {
    if constexpr (F32) return ((const float*)p)[i];
    else return bf2f(((const u16*)p)[i]);
}

// ---- dtype oracle ----
// flags[0]=1 -> float tensors are fp32 (reading them as bf16 pairs yields huge garbage)
// flags[1]=1 -> edge_index stored as int32 (odd int32 words nonzero); 0 -> int64
__global__ __launch_bounds__(256) void detect_kernel(const void* x, const int* ei, int* flags) {
    __shared__ float smax[256];
    __shared__ int sor[256];
    int t = threadIdx.x;
    const u16* xs = (const u16*)x;
    float mx = 0.f;
#pragma unroll
    for (int i = 0; i < 16; ++i) {
        float a = fabsf(bf2f(xs[t * 16 + i]));
        if (!(a == a)) a = 1e30f;  // NaN pattern -> counts as huge
        mx = fmaxf(mx, a);
    }
    int any = 0;
#pragma unroll
    for (int i = 0; i < 8; ++i) any |= ei[2 * (t * 8 + i) + 1];
    smax[t] = mx;
    sor[t] = any;
    __syncthreads();
    for (int s = 128; s > 0; s >>= 1) {
        if (t < s) { smax[t] = fmaxf(smax[t], smax[t + s]); sor[t] |= sor[t + s]; }
        __syncthreads();
    }
    if (t == 0) {
        flags[0] = (smax[0] > 1000.f) ? 1 : 0;
        flags[1] = (sor[0] != 0) ? 1 : 0;
    }
}

// ---- node_transform: h0 = relu(x @ Wnt^T + bnt), x:[N,6], Wnt:[64,6] ----
template <bool F32>
__device__ __forceinline__ void nt_body(const void* x, const void* Wnt, const void* bnt,
                                        float* h, int N) {
    int gid = blockIdx.x * 256 + threadIdx.x;
    if (gid >= N * D) return;
    int n = gid >> 6, c = gid & 63;
    float acc = ld<F32>(bnt, c);
#pragma unroll
    for (int k = 0; k < 6; ++k)
        acc = fmaf(ld<F32>(x, n * 6 + k), ld<F32>(Wnt, c * 6 + k), acc);
    h[gid] = fmaxf(acc, 0.f);
}
__global__ __launch_bounds__(256) void nt_kernel(const int* flags, const void* x, const void* Wnt,
                                                 const void* bnt, float* h, int N) {
    if (flags[0]) nt_body<true>(x, Wnt, bnt, h, N);
    else          nt_body<false>(x, Wnt, bnt, h, N);
}

// ---- m = h @ weight[layer], weight slice [64,64]; one wave per node ----
template <bool F32>
__device__ __forceinline__ void m_body(const float* h, const void* W, int woff, float* m, int N) {
    int lane = threadIdx.x & 63;
    int n = blockIdx.x * 4 + (threadIdx.x >> 6);
    if (n >= N) return;
    const float* hrow = h + (size_t)n * D;
    float acc = 0.f;
#pragma unroll
    for (int k = 0; k < D; ++k)
        acc = fmaf(hrow[k], ld<F32>(W, woff + k * D + lane), acc);
    m[(size_t)n * D + lane] = acc;
}
__global__ __launch_bounds__(256) void m_kernel(const int* flags, const float* h, const void* W,
                                                int woff, float* m, int N) {
    if (flags[0]) m_body<true>(h, W, woff, m, N);
    else          m_body<false>(h, W, woff, m, N);
}

// ---- agg[dst] += m[src]; one wave per edge, lane = channel ----
__global__ __launch_bounds__(256) void scatter_kernel(const int* flags, const float* __restrict__ m,
                                                      const int* __restrict__ ei,
                                                      float* __restrict__ agg, int E, int N) {
    int e = blockIdx.x * 4 + (threadIdx.x >> 6);
    if (e >= E) return;
    int lane = threadIdx.x & 63;
    int src, dst;
    if (flags[1]) { src = ei[e];     dst = ei[E + e]; }         // int32 layout
    else          { src = ei[2 * e]; dst = ei[2 * (E + e)]; }   // int64 layout (low words)
    if ((unsigned)src >= (unsigned)N || (unsigned)dst >= (unsigned)N) return;  // hard safety
    float v = m[(size_t)src * D + lane];
    atomicAdd(&agg[(size_t)dst * D + lane], v);
}

// ---- GRUCell; lane = node, each of 4 waves handles 16 (wave-uniform) channels ----
template <bool F32>
__device__ __forceinline__ void gru_body(const float* agg, const float* h,
                                         const void* Wih, const void* Whh,
                                         const void* bih, const void* bhh,
                                         float* hout, void* obuf, int N) {
    int lane = threadIdx.x & 63;
    int sub = threadIdx.x >> 6;
    int n = blockIdx.x * 64 + lane;
    if (n >= N) return;
    float ar[D], hv[D];
    const float4* a4 = (const float4*)(agg + (size_t)n * D);
    const float4* h4 = (const float4*)(h + (size_t)n * D);
#pragma unroll
    for (int i = 0; i < 16; ++i) {
        float4 v = a4[i];
        ar[4 * i] = v.x; ar[4 * i + 1] = v.y; ar[4 * i + 2] = v.z; ar[4 * i + 3] = v.w;
        float4 w = h4[i];
        hv[4 * i] = w.x; hv[4 * i + 1] = w.y; hv[4 * i + 2] = w.z; hv[4 * i + 3] = w.w;
    }
    int c0 = sub * 16;
#pragma unroll 1
    for (int cc = 0; cc < 16; ++cc) {
        int c = c0 + cc;  // wave-uniform
        float air = ld<F32>(bih, c), aiz = ld<F32>(bih, 64 + c), ain = ld<F32>(bih, 128 + c);
        float ahr = ld<F32>(bhh, c), ahz = ld<F32>(bhh, 64 + c), ahn = ld<F32>(bhh, 128 + c);
#pragma unroll
        for (int k = 0; k < D; ++k) {
            air = fmaf(ar[k], ld<F32>(Wih, c * D + k), air);
            aiz = fmaf(ar[k], ld<F32>(Wih, (64 + c) * D + k), aiz);
            ain = fmaf(ar[k], ld<F32>(Wih, (128 + c) * D + k), ain);
            ahr = fmaf(hv[k], ld<F32>(Whh, c * D + k), ahr);
            ahz = fmaf(hv[k], ld<F32>(Whh, (64 + c) * D + k), ahz);
            ahn = fmaf(hv[k], ld<F32>(Whh, (128 + c) * D + k), ahn);
        }
        float r = 1.f / (1.f + __expf(-(air + ahr)));
        float z = 1.f / (1.f + __expf(-(aiz + ahz)));
        float nx = ain + r * ahn;
        float nn = 1.f - 2.f / (1.f + __expf(2.f * nx));  // tanh, overflow-safe
        float hn = (1.f - z) * nn + z * hv[c];
        if (hout) hout[(size_t)n * D + c] = hn;
        else if (F32) ((float*)obuf)[(size_t)n * D + c] = hn;
        else ((bf16*)obuf)[(size_t)n * D + c] = __float2bfloat16(hn);
    }
}
__global__ __launch_bounds__(256) void gru_kernel(const int* flags, const float* agg, const float* h,
                                                  const void* Wih, const void* Whh,
                                                  const void* bih, const void* bhh,
                                                  float* hout, void* obuf, int N) {
    if (flags[0]) gru_body<true>(agg, h, Wih, Whh, bih, bhh, hout, obuf, N);
    else          gru_body<false>(agg, h, Wih, Whh, bih, bhh, hout, obuf, N);
}

extern "C" void kernel_launch(void* const* d_in, const int* in_sizes, int n_in,
                              void* d_out, int out_size, void* d_ws, size_t ws_size,
                              hipStream_t stream) {
    const void* x   = d_in[0];
    const int*  ei  = (const int*)d_in[1];
    const void* Wnt = d_in[4];
    const void* bnt = d_in[5];
    const void* Wt  = d_in[6];   // [3,64,64]
    const void* Wih = d_in[7];   // [192,64]
    const void* Whh = d_in[8];
    const void* bih = d_in[9];
    const void* bhh = d_in[10];

    int N = in_sizes[0] / 6;
    int E = in_sizes[1] / 2;

    int* flags = (int*)d_ws;
    float* B0 = (float*)((char*)d_ws + 256);
    float* B1 = B0 + (size_t)N * D;
    float* B2 = B1 + (size_t)N * D;

    detect_kernel<<<1, 256, 0, stream>>>(x, ei, flags);
    nt_kernel<<<(N * D + 255) / 256, 256, 0, stream>>>(flags, x, Wnt, bnt, B0, N);

    float* h = B0;
    float* mbuf = B1;
    float* agg = B2;
    for (int layer = 0; layer < 3; ++layer) {
        m_kernel<<<(N + 3) / 4, 256, 0, stream>>>(flags, h, Wt, layer * D * D, mbuf, N);
        hipMemsetAsync(agg, 0, (size_t)N * D * sizeof(float), stream);
        scatter_kernel<<<(E + 3) / 4, 256, 0, stream>>>(flags, mbuf, ei, agg, E, N);
        bool last = (layer == 2);
        gru_kernel<<<(N + 63) / 64, 256, 0, stream>>>(flags, agg, h, Wih, Whh, bih, bhh,
                                                      last ? nullptr : mbuf,
                                                      last ? d_out : nullptr, N);
        float* t = h; h = mbuf; mbuf = t;  // gru wrote h_next into mbuf
    }
}

// Round 6
// 1912.886 us; speedup vs baseline: 1.0727x; 1.0727x over previous
//
#include <hip/hip_runtime.h>
#include <hip/hip_bf16.h>
#include <stdint.h>

#define D 64
typedef __hip_bfloat16 bf16;
typedef unsigned short u16;

__device__ __forceinline__ float bf2f(u16 u) { return __uint_as_float(((uint32_t)u) << 16); }

template <bool F32>
__device__ __forceinline__ float ld(const void* p, int i) {
    if constexpr (F32) return ((const float*)p)[i];
    else return bf2f(((const u16*)p)[i]);
}

// ---- dtype oracle ----
// flags[0]=1 -> float tensors are fp32 (reading them as bf16 pairs yields huge garbage)
// flags[1]=1 -> edge_index stored as int32 (odd int32 words nonzero); 0 -> int64
__global__ __launch_bounds__(256) void detect_kernel(const void* x, const int* ei, int* flags) {
    __shared__ float smax[256];
    __shared__ int sor[256];
    int t = threadIdx.x;
    const u16* xs = (const u16*)x;
    float mx = 0.f;
#pragma unroll
    for (int i = 0; i < 16; ++i) {
        float a = fabsf(bf2f(xs[t * 16 + i]));
        if (!(a == a)) a = 1e30f;  // NaN pattern -> counts as huge
        mx = fmaxf(mx, a);
    }
    int any = 0;
#pragma unroll
    for (int i = 0; i < 8; ++i) any |= ei[2 * (t * 8 + i) + 1];
    smax[t] = mx;
    sor[t] = any;
    __syncthreads();
    for (int s = 128; s > 0; s >>= 1) {
        if (t < s) { smax[t] = fmaxf(smax[t], smax[t + s]); sor[t] |= sor[t + s]; }
        __syncthreads();
    }
    if (t == 0) {
        flags[0] = (smax[0] > 1000.f) ? 1 : 0;
        flags[1] = (sor[0] != 0) ? 1 : 0;
    }
}

// ---- node_transform: h0 = relu(x @ Wnt^T + bnt), x:[N,6], Wnt:[64,6] ----
template <bool F32>
__device__ __forceinline__ void nt_body(const void* x, const void* Wnt, const void* bnt,
                                        float* h, int N) {
    int gid = blockIdx.x * 256 + threadIdx.x;
    if (gid >= N * D) return;
    int n = gid >> 6, c = gid & 63;
    float acc = ld<F32>(bnt, c);
#pragma unroll
    for (int k = 0; k < 6; ++k)
        acc = fmaf(ld<F32>(x, n * 6 + k), ld<F32>(Wnt, c * 6 + k), acc);
    h[gid] = fmaxf(acc, 0.f);
}
__global__ __launch_bounds__(256) void nt_kernel(const int* flags, const void* x, const void* Wnt,
                                                 const void* bnt, float* h, int N) {
    if (flags[0]) nt_body<true>(x, Wnt, bnt, h, N);
    else          nt_body<false>(x, Wnt, bnt, h, N);
}

// ---- m = h @ weight[layer], weight slice [64,64]; one wave per node ----
template <bool F32>
__device__ __forceinline__ void m_body(const float* h, const void* W, int woff, float* m, int N) {
    int lane = threadIdx.x & 63;
    int n = blockIdx.x * 4 + (threadIdx.x >> 6);
    if (n >= N) return;
    const float* hrow = h + (size_t)n * D;
    float acc = 0.f;
#pragma unroll
    for (int k = 0; k < D; ++k)
        acc = fmaf(hrow[k], ld<F32>(W, woff + k * D + lane), acc);
    m[(size_t)n * D + lane] = acc;
}
__global__ __launch_bounds__(256) void m_kernel(const int* flags, const float* h, const void* W,
                                                int woff, float* m, int N) {
    if (flags[0]) m_body<true>(h, W, woff, m, N);
    else          m_body<false>(h, W, woff, m, N);
}

// ---- agg[dst] += m[src]; one wave per edge, lane = channel ----
__global__ __launch_bounds__(256) void scatter_kernel(const int* flags, const float* __restrict__ m,
                                                      const int* __restrict__ ei,
                                                      float* __restrict__ agg, int E, int N) {
    int e = blockIdx.x * 4 + (threadIdx.x >> 6);
    if (e >= E) return;
    int lane = threadIdx.x & 63;
    int src, dst;
    if (flags[1]) { src = ei[e];     dst = ei[E + e]; }         // int32 layout
    else          { src = ei[2 * e]; dst = ei[2 * (E + e)]; }   // int64 layout (low words)
    if ((unsigned)src >= (unsigned)N || (unsigned)dst >= (unsigned)N) return;  // hard safety
    float v = m[(size_t)src * D + lane];
    atomicAdd(&agg[(size_t)dst * D + lane], v);
}

// ---- GRUCell; ROUND-1 PASSING STRUCTURE + spill fix:
//      hv[c] (dynamic index -> forced scratch, 61 MB/launch) replaced by a
//      direct global reload h[n*D+c]; all array indices now compile-time
//      constants => ar/hv stay in VGPRs. launch_bounds(256,1) relaxes VGPR cap.
template <bool F32>
__device__ __forceinline__ void gru_body(const float* agg, const float* h,
                                         const void* Wih, const void* Whh,
                                         const void* bih, const void* bhh,
                                         float* hout, void* obuf, int N) {
    int lane = threadIdx.x & 63;
    int sub = threadIdx.x >> 6;
    int n = blockIdx.x * 64 + lane;
    if (n >= N) return;
    float ar[D], hv[D];
    const float4* a4 = (const float4*)(agg + (size_t)n * D);
    const float4* h4 = (const float4*)(h + (size_t)n * D);
#pragma unroll
    for (int i = 0; i < 16; ++i) {
        float4 v = a4[i];
        ar[4 * i] = v.x; ar[4 * i + 1] = v.y; ar[4 * i + 2] = v.z; ar[4 * i + 3] = v.w;
        float4 w = h4[i];
        hv[4 * i] = w.x; hv[4 * i + 1] = w.y; hv[4 * i + 2] = w.z; hv[4 * i + 3] = w.w;
    }
    int c0 = sub * 16;
#pragma unroll 1
    for (int cc = 0; cc < 16; ++cc) {
        int c = c0 + cc;  // wave-uniform
        float air = ld<F32>(bih, c), aiz = ld<F32>(bih, 64 + c), ain = ld<F32>(bih, 128 + c);
        float ahr = ld<F32>(bhh, c), ahz = ld<F32>(bhh, 64 + c), ahn = ld<F32>(bhh, 128 + c);
#pragma unroll
        for (int k = 0; k < D; ++k) {
            air = fmaf(ar[k], ld<F32>(Wih, c * D + k), air);
            aiz = fmaf(ar[k], ld<F32>(Wih, (64 + c) * D + k), aiz);
            ain = fmaf(ar[k], ld<F32>(Wih, (128 + c) * D + k), ain);
            ahr = fmaf(hv[k], ld<F32>(Whh, c * D + k), ahr);
            ahz = fmaf(hv[k], ld<F32>(Whh, (64 + c) * D + k), ahz);
            ahn = fmaf(hv[k], ld<F32>(Whh, (128 + c) * D + k), ahn);
        }
        float r = 1.f / (1.f + __expf(-(air + ahr)));
        float z = 1.f / (1.f + __expf(-(aiz + ahz)));
        float nx = ain + r * ahn;
        float nn = 1.f - 2.f / (1.f + __expf(2.f * nx));  // tanh, overflow-safe
        float hcur = h[(size_t)n * D + c];                // spill fix: reload, not hv[c]
        float hn = (1.f - z) * nn + z * hcur;
        if (hout) hout[(size_t)n * D + c] = hn;
        else if (F32) ((float*)obuf)[(size_t)n * D + c] = hn;
        else ((bf16*)obuf)[(size_t)n * D + c] = __float2bfloat16(hn);
    }
}
__global__ __launch_bounds__(256, 1) void gru_kernel(const int* flags, const float* agg, const float* h,
                                                     const void* Wih, const void* Whh,
                                                     const void* bih, const void* bhh,
                                                     float* hout, void* obuf, int N) {
    if (flags[0]) gru_body<true>(agg, h, Wih, Whh, bih, bhh, hout, obuf, N);
    else          gru_body<false>(agg, h, Wih, Whh, bih, bhh, hout, obuf, N);
}

extern "C" void kernel_launch(void* const* d_in, const int* in_sizes, int n_in,
                              void* d_out, int out_size, void* d_ws, size_t ws_size,
                              hipStream_t stream) {
    const void* x   = d_in[0];
    const int*  ei  = (const int*)d_in[1];
    const void* Wnt = d_in[4];
    const void* bnt = d_in[5];
    const void* Wt  = d_in[6];   // [3,64,64]
    const void* Wih = d_in[7];   // [192,64]
    const void* Whh = d_in[8];
    const void* bih = d_in[9];
    const void* bhh = d_in[10];

    int N = in_sizes[0] / 6;
    int E = in_sizes[1] / 2;

    int* flags = (int*)d_ws;
    float* B0 = (float*)((char*)d_ws + 256);
    float* B1 = B0 + (size_t)N * D;
    float* B2 = B1 + (size_t)N * D;

    detect_kernel<<<1, 256, 0, stream>>>(x, ei, flags);
    nt_kernel<<<(N * D + 255) / 256, 256, 0, stream>>>(flags, x, Wnt, bnt, B0, N);

    float* h = B0;
    float* mbuf = B1;
    float* agg = B2;
    for (int layer = 0; layer < 3; ++layer) {
        m_kernel<<<(N + 3) / 4, 256, 0, stream>>>(flags, h, Wt, layer * D * D, mbuf, N);
        hipMemsetAsync(agg, 0, (size_t)N * D * sizeof(float), stream);
        scatter_kernel<<<(E + 3) / 4, 256, 0, stream>>>(flags, mbuf, ei, agg, E, N);
        bool last = (layer == 2);
        gru_kernel<<<(N + 63) / 64, 256, 0, stream>>>(flags, agg, h, Wih, Whh, bih, bhh,
                                                      last ? nullptr : mbuf,
                                                      last ? d_out : nullptr, N);
        float* t = h; h = mbuf; mbuf = t;  // gru wrote h_next into mbuf
    }
}